// Round 12
// baseline (357.115 us; speedup 1.0000x reference)
//
#include <hip/hip_runtime.h>

// ToDenseBEVConvolution R12 — 3 dispatches (R11 ledger: boundaries ~12us each
// were the largest controllable block; dense already at fill rate):
//  D1 memset(head): pt+1 encoding, 0 = empty. Only init needed.
//  D2 bev_point_tile: grid = (n/256 tiles) x (16 bins). Block (i,bin) re-reads
//     tile i's coords, LDS-compacts its same-bin points (~16 avg), stages
//     kern[bin] in LDS once, computes [1,64]x[64,128] per point -> f[N,128];
//     head=pt+1 via atomicExch, nxt[pt]=old (0=end). No sort, no gcnt.
//  D3 bev_dense_chain: wave per 2KB output row; coalesced int4 head loads;
//     per occupied element walks the chain in-line (avg len 1.04; nxt is
//     160KB L1/L2-resident, loads overlap f loads); coalesced 1KB stores.
//     Accum dispatch folded in.

#define CIN    64
#define COUT   128
#define BEVH   512
#define BEVW   512
#define HW     (BEVH * BEVW)     // 2^18
#define NBINS  16

// ------------------------------------------------ D2: tiled binned matmul
__global__ __launch_bounds__(256) void bev_point_tile(
    const int*   __restrict__ coords,   // [N,4] (x,h,z,b)
    const float* __restrict__ feats,    // [N,64]
    const float* __restrict__ kern,     // [16,64,128]
    const int*   __restrict__ stride_p, // [1]
    float*       __restrict__ f,        // [N,128]
    int*         __restrict__ head,     // [ncells] init 0; stores pt+1
    int*         __restrict__ nxt,      // [N]; 0 = end-of-chain
    int n)
{
    __shared__ float lk[CIN * COUT];    // 32 KB: kern[bin]
    __shared__ int   list[256];
    __shared__ int   cnt;

    const int blk = blockIdx.x >> 4;    // source 256-point tile
    const int bin = blockIdx.x & 15;

    if (threadIdx.x == 0) cnt = 0;
    __syncthreads();

    const int stride = stride_p[0];
    const int pt = blk * 256 + threadIdx.x;
    if (pt < n) {
        const int k = coords[pt * 4 + 1] / stride;
        if (k == bin) {
            const int s = atomicAdd(&cnt, 1);   // LDS atomic; order irrelevant
            list[s] = pt;
        }
    }
    __syncthreads();
    const int c = cnt;                  // uniform
    if (c == 0) return;                 // uniform exit: no barrier after

    // stage kern[bin] -> LDS (256 thr x 8 float4); kern is 512KB total, L2-hot
    {
        const float4* src = (const float4*)(kern + (size_t)bin * CIN * COUT);
        float4* dst = (float4*)lk;
#pragma unroll
        for (int j = 0; j < 8; ++j)
            dst[j * 256 + threadIdx.x] = src[j * 256 + threadIdx.x];
    }
    __syncthreads();

    const int wave = threadIdx.x >> 6;
    const int lane = threadIdx.x & 63;

    for (int idx = wave; idx < c; idx += 4) {
        const int p = __builtin_amdgcn_readfirstlane(list[idx]); // -> SGPR
        const float* fp = feats + (size_t)p * CIN;
        float ax = 0.f, ay = 0.f, bx = 0.f, by = 0.f;   // 2 acc pairs for ILP
#pragma unroll
        for (int cc = 0; cc < CIN; cc += 2) {
            const float fv0 = fp[cc];                    // s_load (uniform)
            const float fv1 = fp[cc + 1];
            const float2 kv0 = *(const float2*)&lk[cc * COUT + 2 * lane];
            const float2 kv1 = *(const float2*)&lk[(cc + 1) * COUT + 2 * lane];
            ax = fmaf(fv0, kv0.x, ax); ay = fmaf(fv0, kv0.y, ay);
            bx = fmaf(fv1, kv1.x, bx); by = fmaf(fv1, kv1.y, by);
        }
        *(float2*)(f + (size_t)p * COUT + 2 * lane) = make_float2(ax + bx, ay + by);

        if (lane == 0) {
            const int cx = coords[p * 4 + 0];
            const int cz = coords[p * 4 + 2];
            const int cb = coords[p * 4 + 3];
            const int cell = (cb << 18) + ((cx / stride) << 9) + (cz / stride);
            const int old = atomicExch(&head[cell], p + 1);  // spread: cheap
            nxt[p] = old;                                    // 0 = end
        }
    }
}

// --------------- D3: wave-per-row dense output with in-line chain walk
__device__ __forceinline__ float chain_sum(
    int p, const float* __restrict__ f, const int* __restrict__ nxt, int o)
{
    float s = 0.f;
    while (p) {                          // avg len 1.04; nxt L1/L2-resident
        s += f[(size_t)(p - 1) * COUT + o];
        p = nxt[p - 1];
    }
    return s;
}

__global__ __launch_bounds__(256) void bev_dense_chain(
    const float* __restrict__ f,        // [N,128]
    const int*   __restrict__ head,     // [ncells], pt+1 or 0
    const int*   __restrict__ nxt,      // [N]
    float*       __restrict__ out,      // [B,128,512,512]
    int nrows)                          // B*COUT*BEVH
{
    const int wave = threadIdx.x >> 6;
    const int lane = threadIdx.x & 63;
    const int row = blockIdx.x * 4 + wave;      // row = (b<<16)|(o<<9)|x
    if (row >= nrows) return;

    const int x = row & 511;
    const int o = (row >> 9) & 127;             // wave-uniform
    const int b = row >> 16;                    // wave-uniform
    const int* hrow = head + (b << 18) + (x << 9);   // 2KB contiguous head row
    float* const orow = out + (size_t)row * 512;

#pragma unroll
    for (int h = 0; h < 2; ++h) {
        const int z = h * 256 + lane * 4;
        const int4 h4 = *(const int4*)(hrow + z);    // coalesced 1KB/wave
        float4 v = make_float4(0.f, 0.f, 0.f, 0.f);
        if (h4.x) v.x = chain_sum(h4.x, f, nxt, o);
        if (h4.y) v.y = chain_sum(h4.y, f, nxt, o);
        if (h4.z) v.z = chain_sum(h4.z, f, nxt, o);
        if (h4.w) v.w = chain_sum(h4.w, f, nxt, o);
        *(float4*)(orow + z) = v;                    // coalesced 1KB/wave store
    }
}

// ------------------------------------------------------------------- launch
extern "C" void kernel_launch(void* const* d_in, const int* in_sizes, int n_in,
                              void* d_out, int out_size, void* d_ws, size_t ws_size,
                              hipStream_t stream) {
    const int*   coords   = (const int*)d_in[0];
    const float* feats    = (const float*)d_in[1];
    const float* kern     = (const float*)d_in[2];
    const int*   stride_p = (const int*)d_in[3];
    float* out = (float*)d_out;

    const int n      = in_sizes[0] / 4;      // coords is [N,4]
    const int ncells = out_size / COUT;      // B*H*W = 524288

    // Workspace: f | head | nxt
    size_t off = 0;
    float* f = (float*)((char*)d_ws + off);  off += (size_t)n * COUT * sizeof(float);
    int* head = (int*)((char*)d_ws + off);   off += (size_t)ncells * sizeof(int);
    int* nxt  = (int*)((char*)d_ws + off);   off += (size_t)n * sizeof(int);

    // D1: ws re-poisoned to 0xAA before every timed launch -> zero head only
    (void)hipMemsetAsync(head, 0, (size_t)ncells * sizeof(int), stream);

    // D2: (tiles x bins) grid
    const int nblk = (n + 255) / 256;
    bev_point_tile<<<nblk * NBINS, 256, 0, stream>>>(
        coords, feats, kern, stride_p, f, head, nxt, n);

    // D3
    const int nrows = out_size / 512;        // B*COUT*BEVH = 131072
    bev_dense_chain<<<nrows / 4, 256, 0, stream>>>(f, head, nxt, out, nrows);
}